// Round 10
// baseline (429.273 us; speedup 1.0000x reference)
//
#include <hip/hip_runtime.h>
#include <hip/hip_bf16.h>
#include <math.h>

#define NTOK 4096
#define DIMSZ 1024
#define HID 4096
#define NE 8
#define RT2 24   // max sum over experts of ceil(count/256) is 23; pad to 24

typedef unsigned short u16;
typedef unsigned int u32;
typedef __attribute__((ext_vector_type(8))) short bf16x8;
typedef __attribute__((ext_vector_type(4))) float f32x4;

#define AS1 __attribute__((address_space(1)))
#define AS3 __attribute__((address_space(3)))

static __device__ __forceinline__ u16 f2bf(float f) {
    u32 u = __float_as_uint(f);
    u32 r = u + 0x7fffu + ((u >> 16) & 1u);
    return (u16)(r >> 16);
}

static __device__ __forceinline__ u32 pk2bf(float lo, float hi) {
    __hip_bfloat162 h = __float22bfloat162_rn(make_float2(lo, hi));
    return *(u32*)&h;
}

__global__ void k_init(int* counts, int* cursor) {
    if (threadIdx.x < NE) { counts[threadIdx.x] = 0; cursor[threadIdx.x] = 0; }
}

__global__ void k_zero(float* p) {
    int i = blockIdx.x * 1024 + threadIdx.x * 4;
    *(float4*)(p + i) = make_float4(0.f, 0.f, 0.f, 0.f);
}

__global__ __launch_bounds__(256) void k_router(const float* __restrict__ x,
                                                const float* __restrict__ Wg,
                                                int* __restrict__ ids,
                                                int* __restrict__ counts) {
    int wave = threadIdx.x >> 6;
    int lane = threadIdx.x & 63;
    int t = blockIdx.x * 4 + wave;

    const float4* xr = (const float4*)(x + (size_t)t * DIMSZ);
    float4 xv[4];
#pragma unroll
    for (int j = 0; j < 4; j++) xv[j] = xr[j * 64 + lane];

    float s[NE];
#pragma unroll
    for (int e = 0; e < NE; e++) {
        const float4* wr = (const float4*)(Wg + (size_t)e * DIMSZ);
        float p = 0.f;
#pragma unroll
        for (int j = 0; j < 4; j++) {
            float4 w = wr[j * 64 + lane];
            p += xv[j].x * w.x + xv[j].y * w.y + xv[j].z * w.z + xv[j].w * w.w;
        }
#pragma unroll
        for (int m = 32; m >= 1; m >>= 1) p += __shfl_xor(p, m, 64);
        s[e] = p;
    }
    if (lane == 0) {
        int best = 0;
#pragma unroll
        for (int e = 1; e < NE; e++) if (s[e] > s[best]) best = e;
        ids[t] = best;
        atomicAdd(&counts[best], 1);
    }
}

__global__ void k_scan(const int* __restrict__ counts, int* __restrict__ offs) {
    if (threadIdx.x == 0) {
        int a = 0;
        for (int e = 0; e < NE; e++) { offs[e] = a; a += counts[e]; }
    }
}

__global__ __launch_bounds__(256) void k_gather(const float* __restrict__ x,
                                                const int* __restrict__ ids,
                                                const int* __restrict__ offs,
                                                int* __restrict__ cursor,
                                                int* __restrict__ perm,
                                                u16* __restrict__ Xg) {
    int t = blockIdx.x;
    __shared__ int sp;
    if (threadIdx.x == 0) {
        int e = ids[t];
        int p = offs[e] + atomicAdd(&cursor[e], 1);
        perm[p] = t;
        sp = p;
    }
    __syncthreads();
    int p = sp;
    const float4* src = (const float4*)(x + (size_t)t * DIMSZ);
    float4 v = src[threadIdx.x];
    uint2* dst = (uint2*)(Xg + (size_t)p * DIMSZ + threadIdx.x * 4);
    *dst = make_uint2(pk2bf(v.x, v.y), pk2bf(v.z, v.w));
}

// weight transpose+convert: fp32 [E][K][N] -> bf16 [E][N][K] (HBM-roofline pass)
__global__ __launch_bounds__(256) void k_wt(const float* __restrict__ W1,
                                            const float* __restrict__ W2,
                                            u16* __restrict__ W1T,
                                            u16* __restrict__ W2T) {
    int bid = blockIdx.x;
    const float* src;
    u16* dst;
    int K, N, kt, nt;
    if (bid < 8192) {
        int e = bid >> 10, t = bid & 1023;
        kt = t >> 6; nt = t & 63;
        src = W1 + (size_t)e * 1024 * 4096;
        dst = W1T + (size_t)e * 4096 * 1024;
        K = 1024; N = 4096;
    } else {
        int b = bid - 8192;
        int e = b >> 10, t = b & 1023;
        kt = t >> 4; nt = t & 15;
        src = W2 + (size_t)e * 4096 * 1024;
        dst = W2T + (size_t)e * 1024 * 4096;
        K = 4096; N = 1024;
    }
    __shared__ u32 T[32][65];
    int tid = threadIdx.x;
#pragma unroll
    for (int pass = 0; pass < 2; pass++) {
        int kp = (tid >> 4) + pass * 16;
        int nc = (tid & 15) * 4;
        const float* r0 = src + (size_t)(kt * 64 + 2 * kp) * N + nt * 64 + nc;
        float4 a = *(const float4*)r0;
        float4 b = *(const float4*)(r0 + N);
        T[kp][nc + 0] = pk2bf(a.x, b.x);
        T[kp][nc + 1] = pk2bf(a.y, b.y);
        T[kp][nc + 2] = pk2bf(a.z, b.z);
        T[kp][nc + 3] = pk2bf(a.w, b.w);
    }
    __syncthreads();
    int n = tid >> 2;
    int sb = (tid & 3) * 8;
    u16* orow = dst + (size_t)(nt * 64 + n) * K + kt * 64;
#pragma unroll
    for (int p = 0; p < 2; p++) {
        int s = sb + p * 4;
        *(uint4*)(orow + 2 * s) = make_uint4(T[s][n], T[s + 1][n], T[s + 2][n], T[s + 3][n]);
    }
}

// ---------------- grouped GEMM: 256x256 tile, BK=64, 8 waves, 8-phase (m201 port) ---------
// LDS Ls[buf][op][s][256][32]: 2 dbuf x {A,B} x 2 k-slices, 128KB, 1 block/CU.
// Regions per K-tile t (buf=t&1): R0=A.s0, R1=B.s0, R2=A.s1, R3=B.s1.
// Phase schedule (quadrant (s,h), 16 MFMA each):
//   P0=(0,0): read A.s0[h0]+B.s0 | stage (t+1).A.s1   (freed at (t-1).P3)
//   P1=(0,1): read A.s0[h1]      | stage (t+1).B.s1   (freed at (t-1).P2 read, P3 barrier)
//   P2=(1,0): read A.s1[h0]+B.s1 | stage (t+2).A.s0   (A.s0 last read P1, barrier-sep)
//   P3=(1,1): read A.s1[h1]      | stage (t+2).B.s0   (B.s0 last read P0)
// Gate once per K-tile: vmcnt(4) before P0 (allows (t+1).R0,R1 = 4 loads in flight);
// vmcnt(0) only at the final K-tile. Granule swizzle slot^((row>>1)&3): DMA writes
// linear; ds_read_b128 8 lanes per 16B slot-class (uniform) -> conflict-free.
template <int KDIM, int NDIM, int EPI, int KSPLIT>
__global__ __launch_bounds__(512, 2) void k_gemm(const u16* __restrict__ A,
                                                 const u16* __restrict__ Wt,
                                                 const float* __restrict__ biasAll,
                                                 const int* __restrict__ counts,
                                                 const int* __restrict__ offs,
                                                 const int* __restrict__ perm,
                                                 u16* __restrict__ Hout,
                                                 float* __restrict__ Fout) {
    constexpr int NT = NDIM / 256;
    constexpr int NREST = NT * KSPLIT;
    constexpr int NWG = RT2 * NREST;     // 384 (G1) / 192 (G2), both %8==0
    constexpr int CPX = NWG / 8;
    constexpr int KL = KDIM / KSPLIT;
    constexpr int NKT = KL / 64;         // 16 (G1) / 32 (G2), even

    int bid = blockIdx.x;
    int wid = (bid & 7) * CPX + (bid >> 3);   // bijective XCD swizzle
    int x = wid / NREST;                       // row-tile SLOW (L2: A panel resident)
    int rest = wid % NREST;
    int ks = rest % KSPLIT;
    int n0 = (rest / KSPLIT) * 256;
    int kbase = ks * KL;

    int e = -1, lrt = 0, a0 = 0;
#pragma unroll
    for (int i = 0; i < NE; i++) {
        int rt = (counts[i] + 255) >> 8;
        if (e < 0 && x < a0 + rt) { e = i; lrt = x - a0; }
        a0 += rt;
    }
    if (e < 0) return;
    int row0 = offs[e] + lrt * 256;
    int nrows = offs[e] + counts[e] - row0;
    if (nrows > 256) nrows = 256;

    __shared__ u16 Ls[2][2][2][256][32];   // [buf][op][s][row][8*granule] = 128 KiB

    int tid = threadIdx.x;
    int lane = tid & 63;
    int wave = tid >> 6;        // 0..7
    int wr = wave >> 2;         // M half (128 rows)
    int wc = wave & 3;          // N quarter (64 cols)
    int fr = lane & 15, fc = lane >> 4;
    int gsl = fc ^ ((fr >> 1) & 3);   // fragment granule slot (base rows %16==0)

    // staging sources: call c covers granules g = c*512 + tid; r=g>>2, slot=g&3;
    // LDS slot holds global k-granule slot^((r>>1)&3)  (inverse-swizzled source, rule #21)
    const u16 *sA[2], *sB[2];
#pragma unroll
    for (int c = 0; c < 2; c++) {
        int g = c * 512 + tid;
        int r = g >> 2, slot = g & 3;
        int rc = r < nrows ? r : (nrows - 1);
        int kg = (slot ^ ((r >> 1) & 3)) * 8;
        sA[c] = A + (size_t)(row0 + rc) * KDIM + kbase + kg;
        sB[c] = Wt + (size_t)e * NDIM * KDIM + (size_t)(n0 + r) * KDIM + kbase + kg;
    }

    f32x4 acc[8][4] = {};
    bf16x8 bfr[4];

#define STG(OP, SRC, BUF, S, KT)                                                  \
    if ((KT) < NKT) {                                                             \
        __builtin_amdgcn_global_load_lds(                                         \
            (const AS1 void*)((SRC)[0] + (size_t)(KT) * 64 + (S) * 32),           \
            (AS3 void*)(&Ls[BUF][OP][S][0][0] + (wave * 64) * 8), 16, 0, 0);      \
        __builtin_amdgcn_global_load_lds(                                         \
            (const AS1 void*)((SRC)[1] + (size_t)(KT) * 64 + (S) * 32),           \
            (AS3 void*)(&Ls[BUF][OP][S][0][0] + (512 + wave * 64) * 8), 16, 0, 0);\
    }

#define LDA(BUF, S, H, AF)                                                        \
    _Pragma("unroll")                                                             \
    for (int m = 0; m < 4; m++)                                                   \
        AF[m] = *(const bf16x8*)(&Ls[BUF][0][S][0][0] +                           \
                 (wr * 128 + (H) * 64 + m * 16 + fr) * 32 + gsl * 8);

#define LDB(BUF, S)                                                               \
    _Pragma("unroll")                                                             \
    for (int n = 0; n < 4; n++)                                                   \
        bfr[n] = *(const bf16x8*)(&Ls[BUF][1][S][0][0] +                          \
                 (wc * 64 + n * 16 + fr) * 32 + gsl * 8);

#define MM(H, AF)                                                                 \
    __builtin_amdgcn_s_setprio(1);                                                \
    _Pragma("unroll")                                                             \
    for (int m = 0; m < 4; m++)                                                   \
        _Pragma("unroll")                                                         \
        for (int n = 0; n < 4; n++)                                               \
            acc[(H) * 4 + m][n] = __builtin_amdgcn_mfma_f32_16x16x32_bf16(        \
                AF[m], bfr[n], acc[(H) * 4 + m][n], 0, 0, 0);                     \
    __builtin_amdgcn_s_setprio(0);

#define WL()  asm volatile("s_waitcnt lgkmcnt(0)" ::: "memory")
#define BAR() __builtin_amdgcn_s_barrier()
#define SCB() __builtin_amdgcn_sched_barrier(0)

#define KTILE(BUF, OBUF, KT, GATE)                                                \
    {                                                                             \
        bf16x8 af[4];                                                             \
        /* P0 */                                                                  \
        GATE; BAR(); SCB();                                                       \
        LDA(BUF, 0, 0, af); LDB(BUF, 0);                                          \
        STG(0, sA, OBUF, 1, (KT) + 1);                                            \
        WL(); SCB(); MM(0, af); BAR();                                            \
        /* P1 */                                                                  \
        LDA(BUF, 0, 1, af);                                                       \
        STG(1, sB, OBUF, 1, (KT) + 1);                                            \
        BAR(); WL(); SCB(); MM(1, af); BAR();                                     \
        /* P2 */                                                                  \
        LDA(BUF, 1, 0, af); LDB(BUF, 1);                                          \
        STG(0, sA, BUF, 0, (KT) + 2);                                             \
        BAR(); WL(); SCB(); MM(0, af); BAR();                                     \
        /* P3 */                                                                  \
        LDA(BUF, 1, 1, af);                                                       \
        STG(1, sB, BUF, 0, (KT) + 2);                                             \
        BAR(); WL(); SCB(); MM(1, af); BAR();                                     \
    }

#define GATE4 asm volatile("s_waitcnt vmcnt(4)" ::: "memory")
#define GATE0 asm volatile("s_waitcnt vmcnt(0)" ::: "memory")

    // prologue: t0 all 4 regions + t1 R0,R1 (12 loads/thread)
    STG(0, sA, 0, 0, 0);   // t0.A.s0
    STG(1, sB, 0, 0, 0);   // t0.B.s0
    STG(0, sA, 0, 1, 0);   // t0.A.s1
    STG(1, sB, 0, 1, 0);   // t0.B.s1
    STG(0, sA, 1, 0, 1);   // t1.A.s0
    STG(1, sB, 1, 0, 1);   // t1.B.s0

    for (int t = 0; t + 3 < NKT; t += 2) {
        KTILE(0, 1, t, GATE4);
        KTILE(1, 0, t + 1, GATE4);
    }
    KTILE(0, 1, NKT - 2, GATE4);   // stages (NKT-1).R2/R3; (NKT) stages guard off
    KTILE(1, 0, NKT - 1, GATE0);   // drain; all stages guard off

#undef STG
#undef LDA
#undef LDB
#undef MM
#undef WL
#undef BAR
#undef SCB
#undef KTILE
#undef GATE4
#undef GATE0

    // epilogue: acc[am][n], row = wr*128 + (am>>2)*64 + (am&3)*16 + (lane>>4)*4 + j
    int cb = lane & 15;
    int rq = lane >> 4;
#pragma unroll
    for (int am = 0; am < 8; am++) {
        int rbase = wr * 128 + (am >> 2) * 64 + (am & 3) * 16 + rq * 4;
#pragma unroll
        for (int n = 0; n < 4; n++) {
            int col = n0 + wc * 64 + n * 16 + cb;
            float bias = (EPI == 2 && ks != 0) ? 0.f : biasAll[(size_t)e * NDIM + col];
#pragma unroll
            for (int j = 0; j < 4; j++) {
                int r = rbase + j;
                if (r < nrows) {
                    float v = acc[am][n][j] + bias;
                    int p = row0 + r;
                    if (EPI == 1) {
                        float g = 0.5f * v * (1.0f + erff(v * 0.70710678118654752f));
                        Hout[(size_t)p * NDIM + col] = f2bf(g);
                    } else {
                        atomicAdd(&Fout[(size_t)perm[p] * NDIM + col], v);
                    }
                }
            }
        }
    }
}

extern "C" void kernel_launch(void* const* d_in, const int* in_sizes, int n_in,
                              void* d_out, int out_size, void* d_ws, size_t ws_size,
                              hipStream_t stream) {
    const float* x  = (const float*)d_in[0];
    const float* Wg = (const float*)d_in[1];
    const float* W1 = (const float*)d_in[2];
    const float* b1 = (const float*)d_in[3];
    const float* W2 = (const float*)d_in[4];
    const float* b2 = (const float*)d_in[5];
    float* out = (float*)d_out;

    char* ws = (char*)d_ws;
    int* ids    = (int*)(ws + 0);
    int* counts = (int*)(ws + 16384);
    int* offs   = (int*)(ws + 16448);
    int* cursor = (int*)(ws + 16512);
    int* perm   = (int*)(ws + 16576);

    u16* Xg   = (u16*)(ws + 65536);                                  // 8 MiB
    u16* H    = (u16*)(ws + 65536 + 8388608);                        // 32 MiB
    u16* W1T  = (u16*)(ws + 65536 + 8388608 + 33554432);             // 64 MiB
    u16* W2T  = (u16*)(ws + 65536 + 8388608 + 33554432 + 67108864);  // 64 MiB

    k_init<<<dim3(1), dim3(64), 0, stream>>>(counts, cursor);
    k_router<<<dim3(NTOK / 4), dim3(256), 0, stream>>>(x, Wg, ids, counts);
    k_scan<<<dim3(1), dim3(64), 0, stream>>>(counts, offs);
    k_gather<<<dim3(NTOK), dim3(256), 0, stream>>>(x, ids, offs, cursor, perm, Xg);
    k_wt<<<dim3(16384), dim3(256), 0, stream>>>(W1, W2, W1T, W2T);
    k_zero<<<dim3(NTOK * DIMSZ / 1024), dim3(256), 0, stream>>>(out);
    k_gemm<DIMSZ, HID, 1, 1><<<dim3(RT2 * (HID / 256)), dim3(512), 0, stream>>>(
        Xg, W1T, b1, counts, offs, perm, H, (float*)nullptr);
    k_gemm<HID, DIMSZ, 2, 2><<<dim3(RT2 * (DIMSZ / 256) * 2), dim3(512), 0, stream>>>(
        H, W2T, b2, counts, offs, perm, (u16*)nullptr, out);
}